// Round 1
// baseline (596.575 us; speedup 1.0000x reference)
//
#include <hip/hip_runtime.h>
#include <hip/hip_bf16.h>
#include <math.h>

typedef float f32x4 __attribute__((ext_vector_type(4)));
typedef short bf16x8 __attribute__((ext_vector_type(8)));

#define C_DIM 256
#define HID 128

__device__ __forceinline__ unsigned short f2bf(float f) {
  unsigned u = __builtin_bit_cast(unsigned, f);
  u = (u + 0x7fffu + ((u >> 16) & 1u)) >> 16;
  return (unsigned short)u;
}

// Repack W1 [256][128] fp32 -> bf16 MFMA B-fragments.
// Layout: wbuf[((kc*8+nt)*64 + lane)*8 + jj] = bf16(W1[kc*32 + (lane>>4)*8 + jj][nt*16 + (lane&15)])
// (same lane->k mapping as the A fragment below, so the MFMA contraction is
//  correct for any bijective hardware k-layout)
__global__ __launch_bounds__(256) void prep_w_kernel(const float* __restrict__ W1,
                                                     unsigned short* __restrict__ wbuf) {
  int i = blockIdx.x * 256 + threadIdx.x;  // 0..32767
  int jj = i & 7;
  int l  = (i >> 3) & 63;
  int nt = (i >> 9) & 7;
  int kc = i >> 12;
  int k   = kc * 32 + (l >> 4) * 8 + jj;
  int col = nt * 16 + (l & 15);
  wbuf[i] = f2bf(W1[k * HID + col]);
}

// gates[r] = sigmoid( gelu(x[r]@W1 + b1) @ W2 + b2 )
// One wave computes 16 rows; block (4 waves) = 64 rows.
__global__ __launch_bounds__(256) void gates_kernel(
    const float* __restrict__ x, const unsigned short* __restrict__ wbuf,
    const float* __restrict__ b1, const float* __restrict__ W2,
    const float* __restrict__ b2, float* __restrict__ gates, int n_in) {
  const int lane = threadIdx.x & 63;
  const int wid  = threadIdx.x >> 6;
  const int rowbase = blockIdx.x * 64 + wid * 16;
  const int kgrp = lane >> 4;   // 0..3
  int arow = rowbase + (lane & 15);
  if (arow >= n_in) arow = n_in - 1;   // clamp (tail safety; 200000%64==0 anyway)

  f32x4 acc[8];
#pragma unroll
  for (int nt = 0; nt < 8; ++nt) acc[nt] = (f32x4){0.f, 0.f, 0.f, 0.f};

  const float* xrow = x + (size_t)arow * C_DIM + kgrp * 8;
#pragma unroll
  for (int kc = 0; kc < 8; ++kc) {
    f32x4 a0 = *(const f32x4*)(xrow + kc * 32);
    f32x4 a1 = *(const f32x4*)(xrow + kc * 32 + 4);
    bf16x8 af;
#pragma unroll
    for (int j = 0; j < 4; ++j) {
      af[j]     = (short)f2bf(a0[j]);
      af[4 + j] = (short)f2bf(a1[j]);
    }
#pragma unroll
    for (int nt = 0; nt < 8; ++nt) {
      bf16x8 wf = *(const bf16x8*)(wbuf + ((size_t)(kc * 8 + nt) * 64 + lane) * 8);
      acc[nt] = __builtin_amdgcn_mfma_f32_16x16x32_bf16(af, wf, acc[nt], 0, 0, 0);
    }
  }

  // Epilogue: acc[nt][r] = h_pre[row=(lane>>4)*4+r][hid=nt*16+(lane&15)]
  float s[4] = {0.f, 0.f, 0.f, 0.f};
  const int colbase = lane & 15;
  const float inv_sqrt2 = 0.70710678118654752440f;
#pragma unroll
  for (int nt = 0; nt < 8; ++nt) {
    int hid = nt * 16 + colbase;
    float bb = b1[hid];
    float w2 = W2[hid];
#pragma unroll
    for (int r = 0; r < 4; ++r) {
      float v = acc[nt][r] + bb;
      float g = 0.5f * v * (1.0f + erff(v * inv_sqrt2));  // exact GELU
      s[r] += g * w2;
    }
  }
  // reduce over the 16 lanes of each group (sum over hidden)
#pragma unroll
  for (int m = 1; m < 16; m <<= 1) {
#pragma unroll
    for (int r = 0; r < 4; ++r) s[r] += __shfl_xor(s[r], m, 64);
  }
  if (colbase == 0) {
    float bb2 = b2[0];
#pragma unroll
    for (int r = 0; r < 4; ++r) {
      int row = rowbase + kgrp * 4 + r;
      if (row < n_in) {
        float z = s[r] + bb2;
        gates[row] = 1.0f / (1.0f + __expf(-z));
      }
    }
  }
}

// One wave per output row. rows[] is sorted -> binary search the edge range.
__global__ __launch_bounds__(256) void pool_kernel(
    const float* __restrict__ x, const float* __restrict__ vals,
    const int* __restrict__ rows, const int* __restrict__ cols,
    const float* __restrict__ gates, float* __restrict__ out,
    int nnz, int n_out) {
  const int lane = threadIdx.x & 63;
  const int wid  = threadIdx.x >> 6;
  const int r = blockIdx.x * 4 + wid;
  if (r >= n_out) return;

  // lower_bound(rows, r)
  int lo = 0, hi = nnz;
  while (lo < hi) { int mid = (lo + hi) >> 1; if (rows[mid] < r) lo = mid + 1; else hi = mid; }
  const int start = lo;
  // lower_bound(rows, r+1)
  hi = nnz;
  while (lo < hi) { int mid = (lo + hi) >> 1; if (rows[mid] <= r) lo = mid + 1; else hi = mid; }
  const int end = lo;

  f32x4 acc = (f32x4){0.f, 0.f, 0.f, 0.f};
  float mass = 0.f;
  for (int e = start; e < end; ++e) {
    int c = cols[e];
    float gv = vals[e] * gates[c];
    f32x4 xv = *(const f32x4*)(x + (size_t)c * C_DIM + lane * 4);
    acc += gv * xv;
    mass += gv;
  }
  float inv = 1.0f / fmaxf(mass, 1e-8f);
  *(f32x4*)(out + (size_t)r * C_DIM + lane * 4) = acc * inv;
}

extern "C" void kernel_launch(void* const* d_in, const int* in_sizes, int n_in_arrs,
                              void* d_out, int out_size, void* d_ws, size_t ws_size,
                              hipStream_t stream) {
  const float* x    = (const float*)d_in[0];
  const float* vals = (const float*)d_in[1];
  const int*   rows = (const int*)d_in[2];
  const int*   cols = (const int*)d_in[3];
  const float* W1   = (const float*)d_in[4];
  const float* b1   = (const float*)d_in[5];
  const float* W2   = (const float*)d_in[6];
  const float* b2   = (const float*)d_in[7];
  float* out = (float*)d_out;

  const int n_in  = in_sizes[0] / C_DIM;   // 200000
  const int nnz   = in_sizes[1];           // 800000
  const int n_out = out_size / C_DIM;      // 100000

  unsigned short* wbuf = (unsigned short*)d_ws;                 // 64 KiB
  float* gates = (float*)((char*)d_ws + 65536);                 // n_in floats

  prep_w_kernel<<<128, 256, 0, stream>>>(W1, wbuf);
  gates_kernel<<<(n_in + 63) / 64, 256, 0, stream>>>(x, wbuf, b1, W2, b2, gates, n_in);
  pool_kernel<<<(n_out + 3) / 4, 256, 0, stream>>>(x, vals, rows, cols, gates, out, nnz, n_out);
}

// Round 2
// 477.713 us; speedup vs baseline: 1.2488x; 1.2488x over previous
//
#include <hip/hip_runtime.h>
#include <hip/hip_bf16.h>
#include <math.h>

typedef float f32x4 __attribute__((ext_vector_type(4)));
typedef short bf16x8 __attribute__((ext_vector_type(8)));

#define C_DIM 256
#define HID 128

__device__ __forceinline__ unsigned short f2bf(float f) {
  unsigned u = __builtin_bit_cast(unsigned, f);
  u = (u + 0x7fffu + ((u >> 16) & 1u)) >> 16;
  return (unsigned short)u;
}

// Repack W1 [256][128] fp32 -> bf16 MFMA B-fragments (linear 64KB buffer).
// wbuf[((kc*8+nt)*64 + lane)*8 + jj] = bf16(W1[kc*32 + (lane>>4)*8 + jj][nt*16 + (lane&15)])
__global__ __launch_bounds__(256) void prep_w_kernel(const float* __restrict__ W1,
                                                     unsigned short* __restrict__ wbuf) {
  int i = blockIdx.x * 256 + threadIdx.x;  // 0..32767
  int jj = i & 7;
  int l  = (i >> 3) & 63;
  int nt = (i >> 9) & 7;
  int kc = i >> 12;
  int k   = kc * 32 + (l >> 4) * 8 + jj;
  int col = nt * 16 + (l & 15);
  wbuf[i] = f2bf(W1[k * HID + col]);
}

// rows[] is sorted: scatter CSR offsets. offs has n_out+1 entries.
__global__ __launch_bounds__(256) void offs_kernel(const int* __restrict__ rows,
                                                   int* __restrict__ offs,
                                                   int nnz, int n_out) {
  int e = blockIdx.x * 256 + threadIdx.x;
  if (e >= nnz) return;
  int r  = rows[e];
  int rp = (e == 0) ? -1 : rows[e - 1];
  for (int rr = rp + 1; rr <= r; ++rr) offs[rr] = e;   // boundary (and empty-row) fill
  if (e == nnz - 1) {
    for (int rr = r + 1; rr <= n_out; ++rr) offs[rr] = nnz;
  }
}

// gates[r] = sigmoid( gelu(x[r]@W1 + b1) @ W2 + b2 )
// Block = 4 waves x 32 rows = 128 rows. W1 fragments staged in LDS once/block.
__global__ __launch_bounds__(256) void gates_kernel(
    const float* __restrict__ x, const unsigned short* __restrict__ wbuf,
    const float* __restrict__ b1, const float* __restrict__ W2,
    const float* __restrict__ b2, float* __restrict__ gates, int n_in) {
  __shared__ unsigned short ldsw[32768];  // 64 KB
  {
    const f32x4* src = (const f32x4*)wbuf;
    f32x4* dst = (f32x4*)ldsw;
#pragma unroll
    for (int i = 0; i < 16; ++i) dst[threadIdx.x + i * 256] = src[threadIdx.x + i * 256];
  }
  __syncthreads();

  const int lane = threadIdx.x & 63;
  const int wid  = threadIdx.x >> 6;
  const int rowbase = blockIdx.x * 128 + wid * 32;
  const int kgrp = lane >> 4;       // 0..3
  const int colbase = lane & 15;

  int ar0 = rowbase + colbase;        if (ar0 >= n_in) ar0 = n_in - 1;
  int ar1 = rowbase + 16 + colbase;   if (ar1 >= n_in) ar1 = n_in - 1;

  f32x4 acc[2][8];
#pragma unroll
  for (int g = 0; g < 2; ++g)
#pragma unroll
    for (int nt = 0; nt < 8; ++nt) acc[g][nt] = (f32x4){0.f, 0.f, 0.f, 0.f};

  const float* xr0 = x + (size_t)ar0 * C_DIM + kgrp * 8;
  const float* xr1 = x + (size_t)ar1 * C_DIM + kgrp * 8;

#pragma unroll
  for (int kc = 0; kc < 8; ++kc) {
    f32x4 a0l = *(const f32x4*)(xr0 + kc * 32);
    f32x4 a0h = *(const f32x4*)(xr0 + kc * 32 + 4);
    f32x4 a1l = *(const f32x4*)(xr1 + kc * 32);
    f32x4 a1h = *(const f32x4*)(xr1 + kc * 32 + 4);
    bf16x8 af0, af1;
#pragma unroll
    for (int j = 0; j < 4; ++j) {
      af0[j] = (short)f2bf(a0l[j]); af0[4 + j] = (short)f2bf(a0h[j]);
      af1[j] = (short)f2bf(a1l[j]); af1[4 + j] = (short)f2bf(a1h[j]);
    }
#pragma unroll
    for (int nt = 0; nt < 8; ++nt) {
      bf16x8 wf = *(const bf16x8*)(ldsw + ((kc * 8 + nt) * 64 + lane) * 8);
      acc[0][nt] = __builtin_amdgcn_mfma_f32_16x16x32_bf16(af0, wf, acc[0][nt], 0, 0, 0);
      acc[1][nt] = __builtin_amdgcn_mfma_f32_16x16x32_bf16(af1, wf, acc[1][nt], 0, 0, 0);
    }
  }

  // Epilogue: acc[g][nt][r] = h_pre[row=g*16+kgrp*4+r][hid=nt*16+colbase]
  float bb[8], w2[8];
#pragma unroll
  for (int nt = 0; nt < 8; ++nt) {
    int hid = nt * 16 + colbase;
    bb[nt] = b1[hid];
    w2[nt] = W2[hid];
  }
  const float bb2 = b2[0];
  const float kA = 0.7978845608028654f;   // sqrt(2/pi)
  const float kB = 0.044715f;

#pragma unroll
  for (int g = 0; g < 2; ++g) {
    float s[4] = {0.f, 0.f, 0.f, 0.f};
#pragma unroll
    for (int nt = 0; nt < 8; ++nt) {
#pragma unroll
      for (int r = 0; r < 4; ++r) {
        float v = acc[g][nt][r] + bb[nt];
        // tanh-approx GELU via hw exp:
        float z = kA * (v + kB * v * v * v);
        float a = __expf(-2.0f * fabsf(z));
        float t = (1.0f - a) / (1.0f + a);
        t = (z < 0.0f) ? -t : t;
        float gelu = 0.5f * v * (1.0f + t);
        s[r] += gelu * w2[nt];
      }
    }
#pragma unroll
    for (int m = 1; m < 16; m <<= 1) {
#pragma unroll
      for (int r = 0; r < 4; ++r) s[r] += __shfl_xor(s[r], m, 64);
    }
    if (colbase == 0) {
#pragma unroll
      for (int r = 0; r < 4; ++r) {
        int row = rowbase + g * 16 + kgrp * 4 + r;
        if (row < n_in) {
          float zz = s[r] + bb2;
          gates[row] = 1.0f / (1.0f + __expf(-zz));
        }
      }
    }
  }
}

// One wave per output row. CSR offsets precomputed; edge metadata preloaded
// lane-parallel then shfl-broadcast; x gathers unrolled 4-deep.
__global__ __launch_bounds__(256) void pool_kernel(
    const float* __restrict__ x, const float* __restrict__ vals,
    const int* __restrict__ cols, const float* __restrict__ gates,
    const int* __restrict__ offs, float* __restrict__ out, int n_out) {
  const int lane = threadIdx.x & 63;
  const int wid  = threadIdx.x >> 6;
  const int r = blockIdx.x * 4 + wid;
  if (r >= n_out) return;

  const int start = offs[r];
  const int cnt   = offs[r + 1] - start;

  f32x4 acc = (f32x4){0.f, 0.f, 0.f, 0.f};
  float mass = 0.f;

  for (int base = 0; base < cnt; base += 64) {
    const int rem = cnt - base;
    int myc = 0;
    float mygv = 0.f;
    if (lane < rem) {
      int e = start + base + lane;
      myc = cols[e];
      mygv = vals[e] * gates[myc];
    }
    const int m4 = (rem < 64) ? ((rem + 3) & ~3) : 64;
    for (int j = 0; j < m4; j += 4) {
#pragma unroll
      for (int jj = 0; jj < 4; ++jj) {
        const int   c  = __shfl(myc, j + jj, 64);
        const float gv = __shfl(mygv, j + jj, 64);
        const f32x4 xv = *(const f32x4*)(x + (size_t)c * C_DIM + lane * 4);
        acc += gv * xv;
        mass += gv;
      }
    }
  }

  const float inv = 1.0f / fmaxf(mass, 1e-8f);
  f32x4 o = acc * inv;
  __builtin_nontemporal_store(o, (f32x4*)(out + (size_t)r * C_DIM + lane * 4));
}

extern "C" void kernel_launch(void* const* d_in, const int* in_sizes, int n_in_arrs,
                              void* d_out, int out_size, void* d_ws, size_t ws_size,
                              hipStream_t stream) {
  const float* x    = (const float*)d_in[0];
  const float* vals = (const float*)d_in[1];
  const int*   rows = (const int*)d_in[2];
  const int*   cols = (const int*)d_in[3];
  const float* W1   = (const float*)d_in[4];
  const float* b1   = (const float*)d_in[5];
  const float* W2   = (const float*)d_in[6];
  const float* b2   = (const float*)d_in[7];
  float* out = (float*)d_out;

  const int n_in  = in_sizes[0] / C_DIM;   // 200000
  const int nnz   = in_sizes[1];           // 800000
  const int n_out = out_size / C_DIM;      // 100000

  unsigned short* wbuf = (unsigned short*)d_ws;                     // 64 KiB
  float* gates = (float*)((char*)d_ws + (64 << 10));                // n_in f32
  int*   offs  = (int*)((char*)d_ws + (64 << 10) + 4 * (size_t)n_in);  // n_out+1 ints

  prep_w_kernel<<<128, 256, 0, stream>>>(W1, wbuf);
  offs_kernel<<<(nnz + 255) / 256, 256, 0, stream>>>(rows, offs, nnz, n_out);
  gates_kernel<<<(n_in + 127) / 128, 256, 0, stream>>>(x, wbuf, b1, W2, b2, gates, n_in);
  pool_kernel<<<(n_out + 3) / 4, 256, 0, stream>>>(x, vals, cols, gates, offs, out, n_out);
}

// Round 3
// 423.702 us; speedup vs baseline: 1.4080x; 1.1275x over previous
//
#include <hip/hip_runtime.h>
#include <hip/hip_bf16.h>
#include <math.h>

typedef float f32x4 __attribute__((ext_vector_type(4)));
typedef short bf16x8 __attribute__((ext_vector_type(8)));
typedef unsigned short u16x4 __attribute__((ext_vector_type(4)));

#define C_DIM 256
#define HID 128

__device__ __forceinline__ unsigned short f2bf(float f) {
  unsigned u = __builtin_bit_cast(unsigned, f);
  u = (u + 0x7fffu + ((u >> 16) & 1u)) >> 16;
  return (unsigned short)u;
}
__device__ __forceinline__ float bf2f(unsigned short h) {
  return __builtin_bit_cast(float, (unsigned)h << 16);
}

// Repack W1 [256][128] fp32 -> bf16 MFMA B-fragments (linear 64KB buffer).
// wbuf[((kc*8+nt)*64 + lane)*8 + jj] = bf16(W1[kc*32 + (lane>>4)*8 + jj][nt*16 + (lane&15)])
__global__ __launch_bounds__(256) void prep_w_kernel(const float* __restrict__ W1,
                                                     unsigned short* __restrict__ wbuf) {
  int i = blockIdx.x * 256 + threadIdx.x;  // 0..32767
  int jj = i & 7;
  int l  = (i >> 3) & 63;
  int nt = (i >> 9) & 7;
  int kc = i >> 12;
  int k   = kc * 32 + (l >> 4) * 8 + jj;
  int col = nt * 16 + (l & 15);
  wbuf[i] = f2bf(W1[k * HID + col]);
}

// Fused: CSR offset scatter (rows sorted) + gated edge values gv[e]=vals[e]*gates[cols[e]].
__global__ __launch_bounds__(256) void edge_kernel(
    const int* __restrict__ rows, const int* __restrict__ cols,
    const float* __restrict__ vals, const float* __restrict__ gates,
    float* __restrict__ gv, int* __restrict__ offs, int nnz, int n_out) {
  int e = blockIdx.x * 256 + threadIdx.x;
  if (e >= nnz) return;
  int r  = rows[e];
  int rp = (e == 0) ? -1 : rows[e - 1];
  for (int rr = rp + 1; rr <= r; ++rr) offs[rr] = e;
  if (e == nnz - 1) {
    for (int rr = r + 1; rr <= n_out; ++rr) offs[rr] = nnz;
  }
  gv[e] = vals[e] * gates[cols[e]];
}

// gates[r] = sigmoid( gelu(x[r]@W1 + b1) @ W2 + b2 ); also emits bf16 mirror of x.
// Block = 4 waves x 32 rows = 128 rows. W1 fragments staged in LDS once/block.
template <bool WRITE_XBF>
__global__ __launch_bounds__(256) void gates_kernel(
    const float* __restrict__ x, const unsigned short* __restrict__ wbuf,
    const float* __restrict__ b1, const float* __restrict__ W2,
    const float* __restrict__ b2, float* __restrict__ gates,
    unsigned short* __restrict__ xbf, int n_in) {
  __shared__ unsigned short ldsw[32768];  // 64 KB
  {
    const f32x4* src = (const f32x4*)wbuf;
    f32x4* dst = (f32x4*)ldsw;
#pragma unroll
    for (int i = 0; i < 16; ++i) dst[threadIdx.x + i * 256] = src[threadIdx.x + i * 256];
  }
  __syncthreads();

  const int lane = threadIdx.x & 63;
  const int wid  = threadIdx.x >> 6;
  const int rowbase = blockIdx.x * 128 + wid * 32;
  const int kgrp = lane >> 4;       // 0..3
  const int colbase = lane & 15;

  int ar0 = rowbase + colbase;        if (ar0 >= n_in) ar0 = n_in - 1;
  int ar1 = rowbase + 16 + colbase;   if (ar1 >= n_in) ar1 = n_in - 1;

  f32x4 acc[2][8];
#pragma unroll
  for (int g = 0; g < 2; ++g)
#pragma unroll
    for (int nt = 0; nt < 8; ++nt) acc[g][nt] = (f32x4){0.f, 0.f, 0.f, 0.f};

  const float* xr0 = x + (size_t)ar0 * C_DIM + kgrp * 8;
  const float* xr1 = x + (size_t)ar1 * C_DIM + kgrp * 8;

#pragma unroll
  for (int kc = 0; kc < 8; ++kc) {
    f32x4 a0l = *(const f32x4*)(xr0 + kc * 32);
    f32x4 a0h = *(const f32x4*)(xr0 + kc * 32 + 4);
    f32x4 a1l = *(const f32x4*)(xr1 + kc * 32);
    f32x4 a1h = *(const f32x4*)(xr1 + kc * 32 + 4);
    bf16x8 af0, af1;
#pragma unroll
    for (int j = 0; j < 4; ++j) {
      af0[j] = (short)f2bf(a0l[j]); af0[4 + j] = (short)f2bf(a0h[j]);
      af1[j] = (short)f2bf(a1l[j]); af1[4 + j] = (short)f2bf(a1h[j]);
    }
    if (WRITE_XBF) {
      // bf16 mirror of x, row-major (stays cached for the pool gather)
      *(bf16x8*)(xbf + (size_t)ar0 * C_DIM + kc * 32 + kgrp * 8) = af0;
      *(bf16x8*)(xbf + (size_t)ar1 * C_DIM + kc * 32 + kgrp * 8) = af1;
    }
#pragma unroll
    for (int nt = 0; nt < 8; ++nt) {
      bf16x8 wf = *(const bf16x8*)(ldsw + ((kc * 8 + nt) * 64 + lane) * 8);
      acc[0][nt] = __builtin_amdgcn_mfma_f32_16x16x32_bf16(af0, wf, acc[0][nt], 0, 0, 0);
      acc[1][nt] = __builtin_amdgcn_mfma_f32_16x16x32_bf16(af1, wf, acc[1][nt], 0, 0, 0);
    }
  }

  // Epilogue: acc[g][nt][r] = h_pre[row=g*16+kgrp*4+r][hid=nt*16+colbase]
  float bb[8], w2[8];
#pragma unroll
  for (int nt = 0; nt < 8; ++nt) {
    int hid = nt * 16 + colbase;
    bb[nt] = b1[hid];
    w2[nt] = W2[hid];
  }
  const float bb2 = b2[0];
  const float kA = 0.7978845608028654f;   // sqrt(2/pi)
  const float kB = 0.044715f;

#pragma unroll
  for (int g = 0; g < 2; ++g) {
    float s[4] = {0.f, 0.f, 0.f, 0.f};
#pragma unroll
    for (int nt = 0; nt < 8; ++nt) {
#pragma unroll
      for (int r = 0; r < 4; ++r) {
        float v = acc[g][nt][r] + bb[nt];
        float z = kA * (v + kB * v * v * v);
        float a = __expf(-2.0f * fabsf(z));
        float t = (1.0f - a) / (1.0f + a);
        t = (z < 0.0f) ? -t : t;
        float gelu = 0.5f * v * (1.0f + t);
        s[r] += gelu * w2[nt];
      }
    }
#pragma unroll
    for (int m = 1; m < 16; m <<= 1) {
#pragma unroll
      for (int r = 0; r < 4; ++r) s[r] += __shfl_xor(s[r], m, 64);
    }
    if (colbase == 0) {
#pragma unroll
      for (int r = 0; r < 4; ++r) {
        int row = rowbase + g * 16 + kgrp * 4 + r;
        if (row < n_in) {
          float zz = s[r] + bb2;
          gates[row] = 1.0f / (1.0f + __expf(-zz));
        }
      }
    }
  }
}

// One wave per output row; bf16 x-gather (each lane owns 4 channels).
__global__ __launch_bounds__(256) void pool_bf16_kernel(
    const unsigned short* __restrict__ xbf, const float* __restrict__ gv,
    const int* __restrict__ cols, const int* __restrict__ offs,
    float* __restrict__ out, int n_out) {
  const int lane = threadIdx.x & 63;
  const int wid  = threadIdx.x >> 6;
  const int r = blockIdx.x * 4 + wid;
  if (r >= n_out) return;

  const int start = offs[r];
  const int cnt   = offs[r + 1] - start;

  f32x4 acc = (f32x4){0.f, 0.f, 0.f, 0.f};
  float mass = 0.f;

  for (int base = 0; base < cnt; base += 64) {
    const int rem = cnt - base;
    int myc = 0;
    float mygv = 0.f;
    if (lane < rem) {
      int e = start + base + lane;
      myc = cols[e];
      mygv = gv[e];
    }
    const int m4 = (rem < 64) ? ((rem + 3) & ~3) : 64;
    for (int j = 0; j < m4; j += 4) {
#pragma unroll
      for (int jj = 0; jj < 4; ++jj) {
        const int   c = __shfl(myc, j + jj, 64);
        const float g = __shfl(mygv, j + jj, 64);
        const u16x4 xv = *(const u16x4*)(xbf + (size_t)c * C_DIM + lane * 4);
        acc[0] += g * bf2f(xv[0]);
        acc[1] += g * bf2f(xv[1]);
        acc[2] += g * bf2f(xv[2]);
        acc[3] += g * bf2f(xv[3]);
        mass += g;
      }
    }
  }

  const float inv = 1.0f / fmaxf(mass, 1e-8f);
  f32x4 o = acc * inv;
  __builtin_nontemporal_store(o, (f32x4*)(out + (size_t)r * C_DIM + lane * 4));
}

// Fallback: f32 gather straight from x (if ws too small for the bf16 mirror).
__global__ __launch_bounds__(256) void pool_f32_kernel(
    const float* __restrict__ x, const float* __restrict__ gv,
    const int* __restrict__ cols, const int* __restrict__ offs,
    float* __restrict__ out, int n_out) {
  const int lane = threadIdx.x & 63;
  const int wid  = threadIdx.x >> 6;
  const int r = blockIdx.x * 4 + wid;
  if (r >= n_out) return;

  const int start = offs[r];
  const int cnt   = offs[r + 1] - start;

  f32x4 acc = (f32x4){0.f, 0.f, 0.f, 0.f};
  float mass = 0.f;

  for (int base = 0; base < cnt; base += 64) {
    const int rem = cnt - base;
    int myc = 0;
    float mygv = 0.f;
    if (lane < rem) {
      int e = start + base + lane;
      myc = cols[e];
      mygv = gv[e];
    }
    const int m4 = (rem < 64) ? ((rem + 3) & ~3) : 64;
    for (int j = 0; j < m4; j += 4) {
#pragma unroll
      for (int jj = 0; jj < 4; ++jj) {
        const int   c = __shfl(myc, j + jj, 64);
        const float g = __shfl(mygv, j + jj, 64);
        const f32x4 xv = *(const f32x4*)(x + (size_t)c * C_DIM + lane * 4);
        acc += g * xv;
        mass += g;
      }
    }
  }

  const float inv = 1.0f / fmaxf(mass, 1e-8f);
  f32x4 o = acc * inv;
  __builtin_nontemporal_store(o, (f32x4*)(out + (size_t)r * C_DIM + lane * 4));
}

extern "C" void kernel_launch(void* const* d_in, const int* in_sizes, int n_in_arrs,
                              void* d_out, int out_size, void* d_ws, size_t ws_size,
                              hipStream_t stream) {
  const float* x    = (const float*)d_in[0];
  const float* vals = (const float*)d_in[1];
  const int*   rows = (const int*)d_in[2];
  const int*   cols = (const int*)d_in[3];
  const float* W1   = (const float*)d_in[4];
  const float* b1   = (const float*)d_in[5];
  const float* W2   = (const float*)d_in[6];
  const float* b2   = (const float*)d_in[7];
  float* out = (float*)d_out;

  const int n_in  = in_sizes[0] / C_DIM;   // 200000
  const int nnz   = in_sizes[1];           // 800000
  const int n_out = out_size / C_DIM;      // 100000

  // ws layout
  size_t off = 0;
  unsigned short* wbuf = (unsigned short*)((char*)d_ws + off); off += 64 << 10;
  float* gates = (float*)((char*)d_ws + off);                  off += 4 * (size_t)n_in;
  int*   offs  = (int*)((char*)d_ws + off);                    off += 4 * ((size_t)n_out + 1);
  float* gv    = (float*)((char*)d_ws + off);                  off += 4 * (size_t)nnz;
  off = (off + 255) & ~(size_t)255;
  unsigned short* xbf = (unsigned short*)((char*)d_ws + off);
  const size_t need_xbf = off + 2 * (size_t)n_in * C_DIM;
  const bool use_bf16 = (ws_size >= need_xbf);

  prep_w_kernel<<<128, 256, 0, stream>>>(W1, wbuf);
  if (use_bf16) {
    gates_kernel<true><<<(n_in + 127) / 128, 256, 0, stream>>>(x, wbuf, b1, W2, b2, gates, xbf, n_in);
  } else {
    gates_kernel<false><<<(n_in + 127) / 128, 256, 0, stream>>>(x, wbuf, b1, W2, b2, gates, xbf, n_in);
  }
  edge_kernel<<<(nnz + 255) / 256, 256, 0, stream>>>(rows, cols, vals, gates, gv, offs, nnz, n_out);
  if (use_bf16) {
    pool_bf16_kernel<<<(n_out + 3) / 4, 256, 0, stream>>>(xbf, gv, cols, offs, out, n_out);
  } else {
    pool_f32_kernel<<<(n_out + 3) / 4, 256, 0, stream>>>(x, gv, cols, offs, out, n_out);
  }
}